// Round 6
// baseline (85.732 us; speedup 1.0000x reference)
//
#include <hip/hip_runtime.h>

// ---------------- Kernel 1: g/phi convs + 2x2 maxpool + per-block kv partial (no atomics) ----------
// grid = B*32 (one block per batch per pooled row), block = 256
__global__ __launch_bounds__(256) void k1_kv(const float* __restrict__ x,
    const float* __restrict__ w1, const float* __restrict__ b1,
    const float* __restrict__ w22, const float* __restrict__ b22,
    float* __restrict__ kvpart)
{
  __shared__ float xl[64][128];    // [ch][h2*64+w] two image rows
  __shared__ float wlt[64][64];    // [ch][o]  o<32: w1, o>=32: w22 (transposed)
  __shared__ float bl[64];
  __shared__ float phil[32][33];   // [i][p]  (padded)
  __shared__ float glt[32][33];    // [p][j]  (padded)
  int t = threadIdx.x;
  int b = blockIdx.x >> 5, r = blockIdx.x & 31;
  const float* xb = x + ((size_t)b << 18);

  for (int v = t; v < 2048; v += 256) {            // 64ch * 2rows * 64px / 4
    int c = v >> 5, rem = v & 31;
    int h2 = rem >> 4, wv = rem & 15;
    float4 u = *(const float4*)(xb + c*4096 + (2*r + h2)*64 + wv*4);
    float* dst = &xl[c][h2*64 + wv*4];
    dst[0] = u.x; dst[1] = u.y; dst[2] = u.z; dst[3] = u.w;
  }
  for (int v = t; v < 1024; v += 256) {            // w1 (512 vecs) + w22 (512 vecs)
    int half = v >> 9, vv = v & 511;
    int o = vv >> 4;                               // 0..31
    int cb = (vv & 15) * 4;
    const float* src = (half ? w22 : w1) + o*64 + cb;
    float4 u = *(const float4*)src;
    int oo = o + half*32;
    wlt[cb+0][oo] = u.x; wlt[cb+1][oo] = u.y; wlt[cb+2][oo] = u.z; wlt[cb+3][oo] = u.w;
  }
  if (t < 32) bl[t] = b1[t];
  else if (t < 64) bl[t] = b22[t-32];
  __syncthreads();

  int p = t & 31, og = t >> 5;                     // pooled col, output group (8 groups of 4)
  float acc0[4][4], acc1[4][4];                    // [k][pix]
  #pragma unroll
  for (int k = 0; k < 4; k++)
    #pragma unroll
    for (int px = 0; px < 4; px++) { acc0[k][px] = 0.f; acc1[k][px] = 0.f; }

  #pragma unroll 4
  for (int c = 0; c < 64; c++) {
    float2 x0 = *(const float2*)&xl[c][2*p];       // row h2=0, w=2p,2p+1
    float2 x1 = *(const float2*)&xl[c][64 + 2*p];  // row h2=1
    float4 wa = *(const float4*)&wlt[c][og*4];     // w1 outputs
    float4 wb = *(const float4*)&wlt[c][32 + og*4];// w22 outputs
    float xs[4]  = {x0.x, x0.y, x1.x, x1.y};
    float was[4] = {wa.x, wa.y, wa.z, wa.w};
    float wbs[4] = {wb.x, wb.y, wb.z, wb.w};
    #pragma unroll
    for (int k = 0; k < 4; k++)
      #pragma unroll
      for (int px = 0; px < 4; px++) {
        acc0[k][px] += was[k] * xs[px];
        acc1[k][px] += wbs[k] * xs[px];
      }
  }
  #pragma unroll
  for (int k = 0; k < 4; k++) {
    int o = og*4 + k;
    float m1 = fmaxf(fmaxf(acc0[k][0], acc0[k][1]), fmaxf(acc0[k][2], acc0[k][3])) + bl[o];
    float m2 = fmaxf(fmaxf(acc1[k][0], acc1[k][1]), fmaxf(acc1[k][2], acc1[k][3])) + bl[32+o];
    glt[p][o]  = m1;   // g   = maxpool(conv1(x,w1,b1))
    phil[o][p] = m2;   // phi = maxpool(conv1x1(x,w22,b22))
  }
  __syncthreads();

  float* kvp = kvpart + (size_t)blockIdx.x * 1024;
  for (int e = t; e < 1024; e += 256) {            // partial kv[i][j] = sum_{p in this row} phi*g
    int i = e >> 5, j = e & 31;
    float s = 0.f;
    #pragma unroll
    for (int q = 0; q < 32; q++) s += phil[i][q] * glt[q][j];
    kvp[e] = s;                                    // plain store — no zero-init needed
  }
}

// ---------------- Kernel 2: sum kv partials; W[b] = (w3 @ (kv/N)^T) @ w21, bias[b] ----------------
// Stores W TRANSPOSED: Wt[b][k][c].  grid = B, block = 64 (thread = output channel c)
__global__ __launch_bounds__(64) void k2_wmat(const float* __restrict__ kvpart,
    const float* __restrict__ w3, const float* __restrict__ b3,
    const float* __restrict__ w21, const float* __restrict__ b21,
    float* __restrict__ Wt, float* __restrict__ biasv)
{
  __shared__ float kvl[32][32];
  __shared__ float w3t[32][64];    // [j][c]
  __shared__ float w21l[32][64];   // [i][ch]
  __shared__ float b21l[32];
  int t = threadIdx.x, b = blockIdx.x;
  for (int e = t; e < 1024; e += 64) {
    float s = 0.f;
    const float* kp = kvpart + ((size_t)b << 15) + e;   // 32 partials of 1024
    #pragma unroll 8
    for (int r2 = 0; r2 < 32; r2++) s += kp[r2*1024];
    kvl[e>>5][e&31] = s * (1.f/1024.f);
  }
  for (int e = t; e < 2048; e += 64) { int c = e >> 5, j = e & 31; w3t[j][c] = w3[e]; }
  for (int e = t; e < 2048; e += 64) { int i = e >> 6, ch = e & 63; w21l[i][ch] = w21[e]; }
  if (t < 32) b21l[t] = b21[t];
  __syncthreads();

  int c = t;
  float A[32];                                     // A[c][i] = sum_j w3[c,j]*kv[i,j]/N
  #pragma unroll
  for (int i = 0; i < 32; i++) {
    float s = 0.f;
    #pragma unroll
    for (int j = 0; j < 32; j++) s += w3t[j][c] * kvl[i][j];
    A[i] = s;
  }
  float bias = b3[c];
  #pragma unroll
  for (int i = 0; i < 32; i++) bias += A[i] * b21l[i];
  biasv[b*64 + c] = bias;
  float* Wb = Wt + (size_t)b*4096;
  #pragma unroll
  for (int ch = 0; ch < 64; ch++) {
    float s = 0.f;
    #pragma unroll
    for (int i = 0; i < 32; i++) s += A[i] * w21l[i][ch];
    Wb[ch*64 + c] = s;                             // Wt[k=ch][c]
  }
}

// ---------------- Kernel 3: z = W[b]@x + bias, LDS-fed 4c x 8px register tile, BN partials --------
// grid = B*32tiles = 512, block = 256.  pg = t&15 (px group), cg = t>>4 (c group of 4)
__global__ __launch_bounds__(256) void k3_stats(const float* __restrict__ x,
    const float* __restrict__ Wt, const float* __restrict__ biasv,
    float* __restrict__ part)
{
  __shared__ float xt[64][128];    // [k][px]
  __shared__ float wl[64][64];     // [k][c]
  __shared__ float lstat[128];
  int t = threadIdx.x, blk = blockIdx.x;
  int tile = blk & 31, b = blk >> 5;
  const float* xb = x + ((size_t)b << 18) + tile*128;
  for (int v = t; v < 2048; v += 256) {
    int ch = v >> 5, rem = v & 31;
    *(float4*)&xt[ch][rem*4] = *(const float4*)(xb + ch*4096 + rem*4);
  }
  const float* wb = Wt + ((size_t)b << 12);
  for (int v = t; v < 1024; v += 256)              // 4096 floats
    *(float4*)&wl[v >> 4][(v & 15)*4] = *(const float4*)(wb + v*4);
  if (t < 128) lstat[t] = 0.f;
  __syncthreads();

  int pg = t & 15, cg = t >> 4;
  int p0 = pg*4, c0 = cg*4;
  float acc[4][8];
  #pragma unroll
  for (int ci = 0; ci < 4; ci++)
    #pragma unroll
    for (int pj = 0; pj < 8; pj++) acc[ci][pj] = 0.f;

  #pragma unroll 4
  for (int k = 0; k < 64; k++) {
    float4 w4 = *(const float4*)&wl[k][c0];
    float4 xa = *(const float4*)&xt[k][p0];
    float4 xc = *(const float4*)&xt[k][p0 + 64];
    float xs[8] = {xa.x, xa.y, xa.z, xa.w, xc.x, xc.y, xc.z, xc.w};
    float ws[4] = {w4.x, w4.y, w4.z, w4.w};
    #pragma unroll
    for (int ci = 0; ci < 4; ci++)
      #pragma unroll
      for (int pj = 0; pj < 8; pj++) acc[ci][pj] += ws[ci] * xs[pj];
  }

  float4 bias4 = *(const float4*)(biasv + b*64 + c0);
  float bb[4] = {bias4.x, bias4.y, bias4.z, bias4.w};
  #pragma unroll
  for (int ci = 0; ci < 4; ci++) {
    float s1 = 0.f, s2 = 0.f;
    #pragma unroll
    for (int pj = 0; pj < 8; pj++) {
      float z = acc[ci][pj] + bb[ci];
      s1 += z; s2 += z*z;
    }
    #pragma unroll
    for (int off = 1; off < 16; off <<= 1) { s1 += __shfl_xor(s1, off); s2 += __shfl_xor(s2, off); }
    if (pg == 0) { atomicAdd(&lstat[c0+ci], s1); atomicAdd(&lstat[64+c0+ci], s2); }
  }
  __syncthreads();
  if (t < 128) part[blk*128 + t] = lstat[t];
}

// ---------------- Kernel 3r: reduce 512 partials, fold gamma/beta -> per-channel scale/shift -------
__global__ __launch_bounds__(1024) void k3_reduce(const float* __restrict__ part,
    const float* __restrict__ gamma, const float* __restrict__ beta,
    float* __restrict__ stats)
{
  __shared__ float lred[8][128];
  __shared__ float tot[128];
  int tid = threadIdx.x;
  int o = tid & 127, seg = tid >> 7;
  float s = 0.f;
  for (int k = 0; k < 64; k++) s += part[(seg*64 + k)*128 + o];
  lred[seg][o] = s;
  __syncthreads();
  if (tid < 128) {
    float v = 0.f;
    #pragma unroll
    for (int g2 = 0; g2 < 8; g2++) v += lred[g2][tid];
    tot[tid] = v;
  }
  __syncthreads();
  if (tid < 64) {
    const float inv_cnt = 1.f / 65536.f;           // B*HW
    float mu  = tot[tid] * inv_cnt;
    float var = tot[64+tid] * inv_cnt - mu*mu;
    float sc  = gamma[tid] * rsqrtf(var + 1e-5f);
    stats[tid]      = sc;                          // scale
    stats[64+tid]   = beta[tid] - sc*mu;           // shift
  }
}

// ---------------- Kernel 4: recompute z, apply scale/shift, + x, write fp32 ----------------
// grid = 512, block = 256; same register-tile GEMM as k3
__global__ __launch_bounds__(256) void k4_out(const float* __restrict__ x,
    const float* __restrict__ Wt, const float* __restrict__ biasv,
    const float* __restrict__ stats,
    float* __restrict__ out)
{
  __shared__ float xt[64][128];
  __shared__ float wl[64][64];
  int t = threadIdx.x, blk = blockIdx.x;
  int tile = blk & 31, b = blk >> 5;
  const float* xb = x + ((size_t)b << 18) + tile*128;
  for (int v = t; v < 2048; v += 256) {
    int ch = v >> 5, rem = v & 31;
    *(float4*)&xt[ch][rem*4] = *(const float4*)(xb + ch*4096 + rem*4);
  }
  const float* wb = Wt + ((size_t)b << 12);
  for (int v = t; v < 1024; v += 256)
    *(float4*)&wl[v >> 4][(v & 15)*4] = *(const float4*)(wb + v*4);
  __syncthreads();

  int pg = t & 15, cg = t >> 4;
  int p0 = pg*4, c0 = cg*4;
  float acc[4][8];
  #pragma unroll
  for (int ci = 0; ci < 4; ci++)
    #pragma unroll
    for (int pj = 0; pj < 8; pj++) acc[ci][pj] = 0.f;

  #pragma unroll 4
  for (int k = 0; k < 64; k++) {
    float4 w4 = *(const float4*)&wl[k][c0];
    float4 xa = *(const float4*)&xt[k][p0];
    float4 xc = *(const float4*)&xt[k][p0 + 64];
    float xs[8] = {xa.x, xa.y, xa.z, xa.w, xc.x, xc.y, xc.z, xc.w};
    float ws[4] = {w4.x, w4.y, w4.z, w4.w};
    #pragma unroll
    for (int ci = 0; ci < 4; ci++)
      #pragma unroll
      for (int pj = 0; pj < 8; pj++) acc[ci][pj] += ws[ci] * xs[pj];
  }

  float4 bias4 = *(const float4*)(biasv + b*64 + c0);
  float4 sc4   = *(const float4*)(stats + c0);
  float4 sh4   = *(const float4*)(stats + 64 + c0);
  float bb[4] = {bias4.x, bias4.y, bias4.z, bias4.w};
  float scv[4] = {sc4.x, sc4.y, sc4.z, sc4.w};
  float shv[4] = {sh4.x, sh4.y, sh4.z, sh4.w};
  float* ob = out + ((size_t)b << 18) + (size_t)tile*128;
  #pragma unroll
  for (int ci = 0; ci < 4; ci++) {
    int c = c0 + ci;
    float4 xa = *(const float4*)&xt[c][p0];
    float4 xc = *(const float4*)&xt[c][p0 + 64];
    float4 ra, rb;
    ra.x = scv[ci]*(acc[ci][0]+bb[ci]) + shv[ci] + xa.x;
    ra.y = scv[ci]*(acc[ci][1]+bb[ci]) + shv[ci] + xa.y;
    ra.z = scv[ci]*(acc[ci][2]+bb[ci]) + shv[ci] + xa.z;
    ra.w = scv[ci]*(acc[ci][3]+bb[ci]) + shv[ci] + xa.w;
    rb.x = scv[ci]*(acc[ci][4]+bb[ci]) + shv[ci] + xc.x;
    rb.y = scv[ci]*(acc[ci][5]+bb[ci]) + shv[ci] + xc.y;
    rb.z = scv[ci]*(acc[ci][6]+bb[ci]) + shv[ci] + xc.z;
    rb.w = scv[ci]*(acc[ci][7]+bb[ci]) + shv[ci] + xc.w;
    *(float4*)(ob + (size_t)c*4096 + p0)      = ra;
    *(float4*)(ob + (size_t)c*4096 + p0 + 64) = rb;
  }
}

extern "C" void kernel_launch(void* const* d_in, const int* in_sizes, int n_in,
                              void* d_out, int out_size, void* d_ws, size_t ws_size,
                              hipStream_t stream)
{
  const float* x    = (const float*)d_in[0];
  const float* w1   = (const float*)d_in[1];
  const float* b1   = (const float*)d_in[2];
  const float* w21  = (const float*)d_in[3];
  const float* b21  = (const float*)d_in[4];
  const float* w22  = (const float*)d_in[5];
  const float* b22  = (const float*)d_in[6];
  const float* w3   = (const float*)d_in[7];
  const float* b3   = (const float*)d_in[8];
  const float* gamma= (const float*)d_in[9];
  const float* beta = (const float*)d_in[10];

  float* ws     = (float*)d_ws;
  float* kvpart = ws;              // 512*1024 = 524288 floats (per-block kv partials)
  float* Wt     = ws + 524288;     // 65536 (per-batch 64x64, [k][c])
  float* biasv  = ws + 589824;     // 1024
  float* part   = ws + 590848;     // 65536 (512 blocks * 128)
  float* stats  = ws + 656384;     // 128 (scale/shift)

  hipLaunchKernelGGL(k1_kv,     dim3(512), dim3(256),  0, stream, x, w1, b1, w22, b22, kvpart);
  hipLaunchKernelGGL(k2_wmat,   dim3(16),  dim3(64),   0, stream, kvpart, w3, b3, w21, b21, Wt, biasv);
  hipLaunchKernelGGL(k3_stats,  dim3(512), dim3(256),  0, stream, x, Wt, biasv, part);
  hipLaunchKernelGGL(k3_reduce, dim3(1),   dim3(1024), 0, stream, part, gamma, beta, stats);
  hipLaunchKernelGGL(k4_out,    dim3(512), dim3(256),  0, stream, x, Wt, biasv, stats, (float*)d_out);
}

// Round 7
// 63.934 us; speedup vs baseline: 1.3409x; 1.3409x over previous
//
#include <hip/hip_runtime.h>

// ---------------- Kernel 1: g/phi convs + 2x2 maxpool + per-block kv partial (no atomics) ----------
// grid = B*32 (one block per batch per pooled row), block = 256
__global__ __launch_bounds__(256) void k1_kv(const float* __restrict__ x,
    const float* __restrict__ w1, const float* __restrict__ b1,
    const float* __restrict__ w22, const float* __restrict__ b22,
    float* __restrict__ kvpart)
{
  __shared__ float xl[64][128];    // [ch][h2*64+w] two image rows
  __shared__ float wlt[64][64];    // [ch][o]  o<32: w1, o>=32: w22 (transposed)
  __shared__ float bl[64];
  __shared__ float phil[32][33];   // [i][p]  (padded)
  __shared__ float glt[32][33];    // [p][j]  (padded)
  int t = threadIdx.x;
  int b = blockIdx.x >> 5, r = blockIdx.x & 31;
  const float* xb = x + ((size_t)b << 18);

  for (int v = t; v < 2048; v += 256) {            // 64ch * 2rows * 64px / 4
    int c = v >> 5, rem = v & 31;
    int h2 = rem >> 4, wv = rem & 15;
    float4 u = *(const float4*)(xb + c*4096 + (2*r + h2)*64 + wv*4);
    float* dst = &xl[c][h2*64 + wv*4];
    dst[0] = u.x; dst[1] = u.y; dst[2] = u.z; dst[3] = u.w;
  }
  for (int v = t; v < 1024; v += 256) {            // w1 (512 vecs) + w22 (512 vecs)
    int half = v >> 9, vv = v & 511;
    int o = vv >> 4;                               // 0..31
    int cb = (vv & 15) * 4;
    const float* src = (half ? w22 : w1) + o*64 + cb;
    float4 u = *(const float4*)src;
    int oo = o + half*32;
    wlt[cb+0][oo] = u.x; wlt[cb+1][oo] = u.y; wlt[cb+2][oo] = u.z; wlt[cb+3][oo] = u.w;
  }
  if (t < 32) bl[t] = b1[t];
  else if (t < 64) bl[t] = b22[t-32];
  __syncthreads();

  int p = t & 31, og = t >> 5;                     // pooled col, output group (8 groups of 4)
  float acc0[4][4], acc1[4][4];                    // [k][pix]
  #pragma unroll
  for (int k = 0; k < 4; k++)
    #pragma unroll
    for (int px = 0; px < 4; px++) { acc0[k][px] = 0.f; acc1[k][px] = 0.f; }

  #pragma unroll 4
  for (int c = 0; c < 64; c++) {
    float2 x0 = *(const float2*)&xl[c][2*p];       // row h2=0, w=2p,2p+1
    float2 x1 = *(const float2*)&xl[c][64 + 2*p];  // row h2=1
    float4 wa = *(const float4*)&wlt[c][og*4];     // w1 outputs
    float4 wb = *(const float4*)&wlt[c][32 + og*4];// w22 outputs
    float xs[4]  = {x0.x, x0.y, x1.x, x1.y};
    float was[4] = {wa.x, wa.y, wa.z, wa.w};
    float wbs[4] = {wb.x, wb.y, wb.z, wb.w};
    #pragma unroll
    for (int k = 0; k < 4; k++)
      #pragma unroll
      for (int px = 0; px < 4; px++) {
        acc0[k][px] += was[k] * xs[px];
        acc1[k][px] += wbs[k] * xs[px];
      }
  }
  #pragma unroll
  for (int k = 0; k < 4; k++) {
    int o = og*4 + k;
    float m1 = fmaxf(fmaxf(acc0[k][0], acc0[k][1]), fmaxf(acc0[k][2], acc0[k][3])) + bl[o];
    float m2 = fmaxf(fmaxf(acc1[k][0], acc1[k][1]), fmaxf(acc1[k][2], acc1[k][3])) + bl[32+o];
    glt[p][o]  = m1;   // g   = maxpool(conv1(x,w1,b1))
    phil[o][p] = m2;   // phi = maxpool(conv1x1(x,w22,b22))
  }
  __syncthreads();

  float* kvp = kvpart + (size_t)blockIdx.x * 1024;
  for (int e = t; e < 1024; e += 256) {            // partial kv[i][j] = sum_{p in this row} phi*g
    int i = e >> 5, j = e & 31;
    float s = 0.f;
    #pragma unroll
    for (int q = 0; q < 32; q++) s += phil[i][q] * glt[q][j];
    kvp[e] = s;                                    // plain store — no zero-init needed
  }
}

// ---------------- Kernel 1r: coalesced reduce of 32 kv partials per batch (folds 1/N) -------------
// grid = B = 16, block = 1024 (thread = kv element)
__global__ __launch_bounds__(1024) void kv_reduce(const float* __restrict__ kvpart,
    float* __restrict__ kv)
{
  int b = blockIdx.x, e = threadIdx.x;
  const float* kp = kvpart + ((size_t)b << 15) + e;
  float s = 0.f;
  #pragma unroll
  for (int r = 0; r < 32; r++) s += kp[r*1024];    // rows are 1024-contiguous -> coalesced
  kv[b*1024 + e] = s * (1.f/1024.f);
}

// ---------------- Kernel 2: W[b] = (w3 @ kv^T) @ w21, bias[b] ----------------
// Stores W TRANSPOSED: Wt[b][k][c].  grid = B, block = 64 (thread = output channel c)
__global__ __launch_bounds__(64) void k2_wmat(const float* __restrict__ kv,
    const float* __restrict__ w3, const float* __restrict__ b3,
    const float* __restrict__ w21, const float* __restrict__ b21,
    float* __restrict__ Wt, float* __restrict__ biasv)
{
  __shared__ float kvl[32][32];
  __shared__ float w3t[32][64];    // [j][c]
  __shared__ float w21l[32][64];   // [i][ch]
  __shared__ float b21l[32];
  int t = threadIdx.x, b = blockIdx.x;
  for (int e = t; e < 1024; e += 64) kvl[e>>5][e&31] = kv[b*1024 + e];   // already /N
  for (int e = t; e < 2048; e += 64) { int c = e >> 5, j = e & 31; w3t[j][c] = w3[e]; }
  for (int e = t; e < 2048; e += 64) { int i = e >> 6, ch = e & 63; w21l[i][ch] = w21[e]; }
  if (t < 32) b21l[t] = b21[t];
  __syncthreads();

  int c = t;
  float A[32];                                     // A[c][i] = sum_j w3[c,j]*kv[i,j]
  #pragma unroll
  for (int i = 0; i < 32; i++) {
    float s = 0.f;
    #pragma unroll
    for (int j = 0; j < 32; j++) s += w3t[j][c] * kvl[i][j];
    A[i] = s;
  }
  float bias = b3[c];
  #pragma unroll
  for (int i = 0; i < 32; i++) bias += A[i] * b21l[i];
  biasv[b*64 + c] = bias;
  float* Wb = Wt + (size_t)b*4096;
  #pragma unroll
  for (int ch = 0; ch < 64; ch++) {
    float s = 0.f;
    #pragma unroll
    for (int i = 0; i < 32; i++) s += A[i] * w21l[i][ch];
    Wb[ch*64 + c] = s;                             // Wt[k=ch][c]
  }
}

// ---------------- Kernel 3: z = W[b]@x + bias, LDS-fed 4c x 8px register tile, BN partials --------
// grid = B*32tiles = 512, block = 256.  pg = t&15 (px group), cg = t>>4 (c group of 4)
__global__ __launch_bounds__(256) void k3_stats(const float* __restrict__ x,
    const float* __restrict__ Wt, const float* __restrict__ biasv,
    float* __restrict__ part)
{
  __shared__ float xt[64][128];    // [k][px]
  __shared__ float wl[64][64];     // [k][c]
  __shared__ float lstat[128];
  int t = threadIdx.x, blk = blockIdx.x;
  int tile = blk & 31, b = blk >> 5;
  const float* xb = x + ((size_t)b << 18) + tile*128;
  for (int v = t; v < 2048; v += 256) {
    int ch = v >> 5, rem = v & 31;
    *(float4*)&xt[ch][rem*4] = *(const float4*)(xb + ch*4096 + rem*4);
  }
  const float* wb = Wt + ((size_t)b << 12);
  for (int v = t; v < 1024; v += 256)              // 4096 floats
    *(float4*)&wl[v >> 4][(v & 15)*4] = *(const float4*)(wb + v*4);
  if (t < 128) lstat[t] = 0.f;
  __syncthreads();

  int pg = t & 15, cg = t >> 4;
  int p0 = pg*4, c0 = cg*4;
  float acc[4][8];
  #pragma unroll
  for (int ci = 0; ci < 4; ci++)
    #pragma unroll
    for (int pj = 0; pj < 8; pj++) acc[ci][pj] = 0.f;

  #pragma unroll 4
  for (int k = 0; k < 64; k++) {
    float4 w4 = *(const float4*)&wl[k][c0];
    float4 xa = *(const float4*)&xt[k][p0];
    float4 xc = *(const float4*)&xt[k][p0 + 64];
    float xs[8] = {xa.x, xa.y, xa.z, xa.w, xc.x, xc.y, xc.z, xc.w};
    float ws[4] = {w4.x, w4.y, w4.z, w4.w};
    #pragma unroll
    for (int ci = 0; ci < 4; ci++)
      #pragma unroll
      for (int pj = 0; pj < 8; pj++) acc[ci][pj] += ws[ci] * xs[pj];
  }

  float4 bias4 = *(const float4*)(biasv + b*64 + c0);
  float bb[4] = {bias4.x, bias4.y, bias4.z, bias4.w};
  #pragma unroll
  for (int ci = 0; ci < 4; ci++) {
    float s1 = 0.f, s2 = 0.f;
    #pragma unroll
    for (int pj = 0; pj < 8; pj++) {
      float z = acc[ci][pj] + bb[ci];
      s1 += z; s2 += z*z;
    }
    #pragma unroll
    for (int off = 1; off < 16; off <<= 1) { s1 += __shfl_xor(s1, off); s2 += __shfl_xor(s2, off); }
    if (pg == 0) { atomicAdd(&lstat[c0+ci], s1); atomicAdd(&lstat[64+c0+ci], s2); }
  }
  __syncthreads();
  if (t < 128) part[blk*128 + t] = lstat[t];
}

// ---------------- Kernel 3r: reduce 512 partials, fold gamma/beta -> per-channel scale/shift -------
__global__ __launch_bounds__(1024) void k3_reduce(const float* __restrict__ part,
    const float* __restrict__ gamma, const float* __restrict__ beta,
    float* __restrict__ stats)
{
  __shared__ float lred[8][128];
  __shared__ float tot[128];
  int tid = threadIdx.x;
  int o = tid & 127, seg = tid >> 7;
  float s = 0.f;
  for (int k = 0; k < 64; k++) s += part[(seg*64 + k)*128 + o];
  lred[seg][o] = s;
  __syncthreads();
  if (tid < 128) {
    float v = 0.f;
    #pragma unroll
    for (int g2 = 0; g2 < 8; g2++) v += lred[g2][tid];
    tot[tid] = v;
  }
  __syncthreads();
  if (tid < 64) {
    const float inv_cnt = 1.f / 65536.f;           // B*HW
    float mu  = tot[tid] * inv_cnt;
    float var = tot[64+tid] * inv_cnt - mu*mu;
    float sc  = gamma[tid] * rsqrtf(var + 1e-5f);
    stats[tid]      = sc;                          // scale
    stats[64+tid]   = beta[tid] - sc*mu;           // shift
  }
}

// ---------------- Kernel 4: recompute z, apply scale/shift, + x, write fp32 ----------------
// grid = 512, block = 256; same register-tile GEMM as k3
__global__ __launch_bounds__(256) void k4_out(const float* __restrict__ x,
    const float* __restrict__ Wt, const float* __restrict__ biasv,
    const float* __restrict__ stats,
    float* __restrict__ out)
{
  __shared__ float xt[64][128];
  __shared__ float wl[64][64];
  int t = threadIdx.x, blk = blockIdx.x;
  int tile = blk & 31, b = blk >> 5;
  const float* xb = x + ((size_t)b << 18) + tile*128;
  for (int v = t; v < 2048; v += 256) {
    int ch = v >> 5, rem = v & 31;
    *(float4*)&xt[ch][rem*4] = *(const float4*)(xb + ch*4096 + rem*4);
  }
  const float* wb = Wt + ((size_t)b << 12);
  for (int v = t; v < 1024; v += 256)
    *(float4*)&wl[v >> 4][(v & 15)*4] = *(const float4*)(wb + v*4);
  __syncthreads();

  int pg = t & 15, cg = t >> 4;
  int p0 = pg*4, c0 = cg*4;
  float acc[4][8];
  #pragma unroll
  for (int ci = 0; ci < 4; ci++)
    #pragma unroll
    for (int pj = 0; pj < 8; pj++) acc[ci][pj] = 0.f;

  #pragma unroll 4
  for (int k = 0; k < 64; k++) {
    float4 w4 = *(const float4*)&wl[k][c0];
    float4 xa = *(const float4*)&xt[k][p0];
    float4 xc = *(const float4*)&xt[k][p0 + 64];
    float xs[8] = {xa.x, xa.y, xa.z, xa.w, xc.x, xc.y, xc.z, xc.w};
    float ws[4] = {w4.x, w4.y, w4.z, w4.w};
    #pragma unroll
    for (int ci = 0; ci < 4; ci++)
      #pragma unroll
      for (int pj = 0; pj < 8; pj++) acc[ci][pj] += ws[ci] * xs[pj];
  }

  float4 bias4 = *(const float4*)(biasv + b*64 + c0);
  float4 sc4   = *(const float4*)(stats + c0);
  float4 sh4   = *(const float4*)(stats + 64 + c0);
  float bb[4] = {bias4.x, bias4.y, bias4.z, bias4.w};
  float scv[4] = {sc4.x, sc4.y, sc4.z, sc4.w};
  float shv[4] = {sh4.x, sh4.y, sh4.z, sh4.w};
  float* ob = out + ((size_t)b << 18) + (size_t)tile*128;
  #pragma unroll
  for (int ci = 0; ci < 4; ci++) {
    int c = c0 + ci;
    float4 xa = *(const float4*)&xt[c][p0];
    float4 xc = *(const float4*)&xt[c][p0 + 64];
    float4 ra, rb;
    ra.x = scv[ci]*(acc[ci][0]+bb[ci]) + shv[ci] + xa.x;
    ra.y = scv[ci]*(acc[ci][1]+bb[ci]) + shv[ci] + xa.y;
    ra.z = scv[ci]*(acc[ci][2]+bb[ci]) + shv[ci] + xa.z;
    ra.w = scv[ci]*(acc[ci][3]+bb[ci]) + shv[ci] + xa.w;
    rb.x = scv[ci]*(acc[ci][4]+bb[ci]) + shv[ci] + xc.x;
    rb.y = scv[ci]*(acc[ci][5]+bb[ci]) + shv[ci] + xc.y;
    rb.z = scv[ci]*(acc[ci][6]+bb[ci]) + shv[ci] + xc.z;
    rb.w = scv[ci]*(acc[ci][7]+bb[ci]) + shv[ci] + xc.w;
    *(float4*)(ob + (size_t)c*4096 + p0)      = ra;
    *(float4*)(ob + (size_t)c*4096 + p0 + 64) = rb;
  }
}

extern "C" void kernel_launch(void* const* d_in, const int* in_sizes, int n_in,
                              void* d_out, int out_size, void* d_ws, size_t ws_size,
                              hipStream_t stream)
{
  const float* x    = (const float*)d_in[0];
  const float* w1   = (const float*)d_in[1];
  const float* b1   = (const float*)d_in[2];
  const float* w21  = (const float*)d_in[3];
  const float* b21  = (const float*)d_in[4];
  const float* w22  = (const float*)d_in[5];
  const float* b22  = (const float*)d_in[6];
  const float* w3   = (const float*)d_in[7];
  const float* b3   = (const float*)d_in[8];
  const float* gamma= (const float*)d_in[9];
  const float* beta = (const float*)d_in[10];

  float* ws     = (float*)d_ws;
  float* kvpart = ws;              // 512*1024 = 524288 (per-block kv partials)
  float* kv     = ws + 524288;     // 16384 (reduced, already /N)
  float* Wt     = ws + 540672;     // 65536 (per-batch 64x64, [k][c])
  float* biasv  = ws + 606208;     // 1024
  float* part   = ws + 607232;     // 65536 (512 blocks * 128)
  float* stats  = ws + 672768;     // 128 (scale/shift)

  hipLaunchKernelGGL(k1_kv,     dim3(512), dim3(256),  0, stream, x, w1, b1, w22, b22, kvpart);
  hipLaunchKernelGGL(kv_reduce, dim3(16),  dim3(1024), 0, stream, kvpart, kv);
  hipLaunchKernelGGL(k2_wmat,   dim3(16),  dim3(64),   0, stream, kv, w3, b3, w21, b21, Wt, biasv);
  hipLaunchKernelGGL(k3_stats,  dim3(512), dim3(256),  0, stream, x, Wt, biasv, part);
  hipLaunchKernelGGL(k3_reduce, dim3(1),   dim3(1024), 0, stream, part, gamma, beta, stats);
  hipLaunchKernelGGL(k4_out,    dim3(512), dim3(256),  0, stream, x, Wt, biasv, stats, (float*)d_out);
}